// Round 12
// baseline (1446.766 us; speedup 1.0000x reference)
//
#include <hip/hip_runtime.h>
#include <hip/hip_fp16.h>

#define LDIM 200
#define BDIM 512
#define IDIM 512
#define HDIM 512
#define GDIM 1536  // 3*H
#define NGRP 16    // batch groups (32 rows each)
#define NCOL 16    // col groups   (32 h-cols each)

typedef _Float16 f16x8 __attribute__((ext_vector_type(8)));
typedef _Float16 f16x4 __attribute__((ext_vector_type(4)));
typedef float    f32x4 __attribute__((ext_vector_type(4)));
typedef unsigned int u32x4 __attribute__((ext_vector_type(4)));

// ---------------------------------------------------------------------------
// k_init: seed hb2 buf0 with {h0 payload, seq=0}; INVALIDATE bufs 1,2 with
// seq=0xFFFFFFFF (never equals any step) — kills the cross-replay stale-seq
// false positive (buf1 held seq=199 from the previous replay, which matched
// the s=199 poll and leaked the prior replay's h into the last step).
// ---------------------------------------------------------------------------
__global__ __launch_bounds__(256) void k_init(
    const float* __restrict__ h0, u32x4* __restrict__ hb2)
{
    int u = blockIdx.x * 256 + threadIdx.x;
    if (u >= BDIM * HDIM / 4) return;
    const int row = u >> 7, col4 = u & 127;
    const float4 v = *(const float4*)(h0 + (size_t)row * HDIM + col4 * 4);
    union { f16x4 h; unsigned int d[2]; } pk;
    pk.h[0] = (_Float16)v.x; pk.h[1] = (_Float16)v.y;
    pk.h[2] = (_Float16)v.z; pk.h[3] = (_Float16)v.w;
    u32x4 st; st[0] = pk.d[0]; st[1] = pk.d[1]; st[2] = 0u; st[3] = 0u;
    hb2[u] = st;
    u32x4 inv; inv[0] = 0u; inv[1] = 0u;
    inv[2] = 0xFFFFFFFFu; inv[3] = 0xFFFFFFFFu;
    hb2[u + 65536]  = inv;   // buf1: stale-seq kill
    hb2[u + 131072] = inv;   // buf2: stale-seq kill
}

// ---------------------------------------------------------------------------
// k_pack_wfi: pack w_ih (f32 [1536][512]) into MFMA B-fragment order, f16.
// (round-3 verified)
// ---------------------------------------------------------------------------
__global__ __launch_bounds__(256) void k_pack_wfi(
    const float* __restrict__ w, f16x8* __restrict__ wf)
{
    int u = blockIdx.x * 256 + threadIdx.x;
    if (u >= (GDIM / 16) * 16 * 64) return;
    const int lane = u & 63;
    const int kk   = (u >> 6) & 15;
    const int ntg  = u >> 10;
    const int n = ntg * 16 + (lane & 15);
    const int k = kk * 32 + (lane >> 4) * 8;
    const float* src = w + (size_t)n * IDIM + k;
    f16x8 v;
    #pragma unroll
    for (int j = 0; j < 8; ++j) v[j] = (_Float16)src[j];
    wf[u] = v;
}

// ---------------------------------------------------------------------------
// k_pack_wfh: pack w_hh into per-colgroup fragment order. (round-3 verified)
// ---------------------------------------------------------------------------
__global__ __launch_bounds__(256) void k_pack_wfh(
    const float* __restrict__ w, f16x8* __restrict__ wf)
{
    int u = blockIdx.x * 256 + threadIdx.x;
    if (u >= NCOL * 6 * 16 * 64) return;
    const int lane = u & 63;
    const int kk   = (u >> 6) & 15;
    const int cw   = u >> 10;
    const int wv   = cw % 6;
    const int c    = cw / 6;
    const int n_local = wv * 16 + (lane & 15);
    const int gate    = n_local >> 5;
    const int j_local = n_local & 31;
    const int n = gate * 512 + c * 32 + j_local;
    const int k = kk * 32 + (lane >> 4) * 8;
    const float* src = w + (size_t)n * HDIM + k;
    f16x8 v;
    #pragma unroll
    for (int j = 0; j < 8; ++j) v[j] = (_Float16)src[j];
    wf[u] = v;
}

// ---------------------------------------------------------------------------
// K1 v3: gx = x @ w_ih^T + b_ih (f16 out).  Round-6/7-verified structure;
// coalesced A-staging (128 consecutive lanes read 128 consecutive float4).
// First-call numerics verified in round 11 (absmax 0.0039).
// ---------------------------------------------------------------------------
__global__ __launch_bounds__(256, 2) void k_gemm_gx(
    const float* __restrict__ x, const f16x8* __restrict__ wfi,
    const float* __restrict__ bih, _Float16* __restrict__ gx)
{
    const int bid  = blockIdx.x;
    const int xcd  = bid & 7;
    const int slot = bid >> 3;          // 0..599
    const int gl   = slot / 3;          // 0..199
    const int ng   = slot % 3;          // 0..2
    const int m0   = (xcd * 200 + gl) * 64;
    const int n0   = ng * 512;

    const int t   = threadIdx.x;
    const int wid = t >> 6;             // n-quarter 0..3
    const int l   = t & 63;

    __shared__ __align__(16) _Float16 As[64 * 512];    // 64KB, XOR-swizzled

    // --- coalesced A staging: row = it*2 + (t>>7), float4 col = t&127 ---
    {
        const int rhalf = t >> 7;        // 0 or 1
        const int cq    = t & 127;       // float4 index within the 512-f32 row
        const int b0    = m0 & 511;      // batch row base
        const int lx    = m0 >> 9;       // sequence index
        const float* base = x + ((size_t)b0 * LDIM + lx) * IDIM + cq * 4;
        #pragma unroll
        for (int it = 0; it < 32; ++it) {
            const int r = it * 2 + rhalf;
            const float4 v = *(const float4*)(base + (size_t)r * LDIM * IDIM);
            f16x4 hq;
            hq[0] = (_Float16)v.x; hq[1] = (_Float16)v.y;
            hq[2] = (_Float16)v.z; hq[3] = (_Float16)v.w;
            union { f16x4 h; unsigned long long u; } cvt; cvt.h = hq;
            const int byte = (r * 1024 + cq * 8) ^ ((r & 7) << 4);
            *(unsigned long long*)((char*)As + byte) = cvt.u;
        }
    }
    __syncthreads();

    const f16x8* bp = wfi + (size_t)((ng * 4 + wid) * 8) * 1024 + l;
    const int kb8   = (l >> 4) * 16;
    const int rbase = l & 15;

    f32x4 acc[4][8] = {};

    for (int kk = 0; kk < 16; ++kk) {
        f16x8 a[4];
        #pragma unroll
        for (int mt = 0; mt < 4; ++mt) {
            const int r = mt * 16 + rbase;
            const int byte = (r * 1024 + kk * 64 + kb8) ^ ((r & 7) << 4);
            a[mt] = *(const f16x8*)((const char*)As + byte);
        }
        const f16x8* bk = bp + kk * 64;
        #pragma unroll
        for (int nt = 0; nt < 8; ++nt) {
            const f16x8 bf = bk[(size_t)nt * 1024];
            #pragma unroll
            for (int mt = 0; mt < 4; ++mt)
                acc[mt][nt] = __builtin_amdgcn_mfma_f32_16x16x32_f16(a[mt], bf, acc[mt][nt], 0, 0, 0);
        }
    }

    #pragma unroll
    for (int nt = 0; nt < 8; ++nt) {
        const int n = n0 + wid * 128 + nt * 16 + (l & 15);
        const float bv = bih[n];
        #pragma unroll
        for (int mt = 0; mt < 4; ++mt) {
            #pragma unroll
            for (int r = 0; r < 4; ++r) {
                const int m = m0 + mt * 16 + (l >> 4) * 4 + r;
                gx[(size_t)m * GDIM + n] = (_Float16)(acc[mt][nt][r] + bv);
            }
        }
    }
}

// ---------------------------------------------------------------------------
// K2: persistent recurrence.  (round-7 verified, byte-identical)
// 256 blocks = 16 batch-groups x 16 col-groups, 384 threads. w_hh slice in
// registers. Exchange: each 16B unit = {f16x4 h payload, seq, seq}; producer
// fires ONE dwordx4 sc0sc1 store; consumers poll their own units until
// seq == s. One IF round-trip per step. 3-buffer rotation (skew<=1 proof).
// ---------------------------------------------------------------------------
__global__ __launch_bounds__(384) void k_recur(
    const _Float16* __restrict__ gx, const float* __restrict__ att,
    const float* __restrict__ h0, const f16x8* __restrict__ wfh,
    const float* __restrict__ bhh, char* __restrict__ hb2c,
    float* __restrict__ out, float* __restrict__ hx)
{
    const int bid = blockIdx.x;
    const int g = bid >> 4;
    const int c = bid & 15;
    const int t = threadIdx.x;
    const int w = t >> 6;                        // 0..5
    const int l = t & 63;

    __shared__ __align__(16) _Float16 h16[32 * 512];   // 32KB, XOR-swizzled
    __shared__ float ghsT[32][100];                    // gh slice [row][n]

    // --- B fragments: wave w holds its 16 kk-frags in registers forever ---
    f16x8 B[16];
    {
        const f16x8* p = wfh + (size_t)(c * 6 + w) * 1024 + l;
        #pragma unroll
        for (int kk = 0; kk < 16; ++kk) B[kk] = p[kk * 64];
    }

    // --- gate-phase mapping: thread t<256 owns row i, cols j4..j4+3 ---
    const int i  = t >> 3;
    const int j4 = (t & 7) * 4;

    float bhr[4], bhz[4], bhn[4], hv[4];
    if (t < 256) {
        const float4 r4 = *(const float4*)(bhh + c * 32 + j4);
        const float4 z4 = *(const float4*)(bhh + 512 + c * 32 + j4);
        const float4 n4 = *(const float4*)(bhh + 1024 + c * 32 + j4);
        bhr[0]=r4.x; bhr[1]=r4.y; bhr[2]=r4.z; bhr[3]=r4.w;
        bhz[0]=z4.x; bhz[1]=z4.y; bhz[2]=z4.z; bhz[3]=z4.w;
        bhn[0]=n4.x; bhn[1]=n4.y; bhn[2]=n4.z; bhn[3]=n4.w;
        const float4 h4 = *(const float4*)(h0 + (size_t)(g * 32 + i) * 512 + c * 32 + j4);
        hv[0]=h4.x; hv[1]=h4.y; hv[2]=h4.z; hv[3]=h4.w;
    }

    const int ib = (l >> 4) * 4;
    const int nl = w * 16 + (l & 15);
    const int k8 = (l >> 4) * 8;
    const int rr0 = l & 15;
    const int rr1 = rr0 + 16;

    // --- prologue: gate inputs for step 0 ---
    f16x4 cr = {}, cz = {}, cn = {};
    float ca = 0.f;
    if (t < 256) {
        const _Float16* gp = gx + ((size_t)(g * 32 + i)) * GDIM + c * 32 + j4;
        cr = *(const f16x4*)(gp);
        cz = *(const f16x4*)(gp + 512);
        cn = *(const f16x4*)(gp + 1024);
        ca = att[g * 32 + i];
    }

    int rd = 0;                                  // hb2 read buffer = s % 3
    for (int s = 0; s < LDIM; ++s) {
        // --- fused poll+load: wait until all 16 of my units carry seq==s ---
        u32x4 vv[16];
        if (t < 256) {
            const char* hbase = hb2c
                + ((size_t)rd * 65536 + (size_t)g * 4096 + t) * 16;
            bool again = true;
            while (again) {
                #pragma unroll
                for (int q = 0; q < 16; ++q)
                    asm volatile("global_load_dwordx4 %0, %1, off sc0 sc1"
                                 : "=v"(vv[q]) : "v"(hbase + (size_t)q * 4096));
                asm volatile("s_waitcnt vmcnt(0)" ::: "memory");
                again = false;
                #pragma unroll
                for (int q = 0; q < 16; ++q)
                    again |= (vv[q][2] != (unsigned)s);
            }
            __builtin_amdgcn_sched_barrier(0);
            #pragma unroll
            for (int q = 0; q < 16; ++q) {
                const int idx = q * 256 + t;     // u64 payload, row-major
                const int row = idx >> 7;        // 128 units per row
                const int c8  = idx & 127;
                const int byte = (row * 1024 + c8 * 8) ^ ((row & 7) << 4);
                union { unsigned int d[2]; unsigned long long u; } m;
                m.d[0] = vv[q][0]; m.d[1] = vv[q][1];
                *(unsigned long long*)((char*)h16 + byte) = m.u;
            }
        }

        // --- 1-step-ahead gate prefetch (hidden under MFMA + gates) ---
        f16x4 nr = {}, nz = {}, nn2 = {};
        float na = 0.f;
        if (t < 256) {
            const int sn = (s < LDIM - 1) ? s + 1 : s;
            const _Float16* gp = gx + ((size_t)sn * BDIM + g * 32 + i) * GDIM + c * 32 + j4;
            nr  = *(const f16x4*)(gp);
            nz  = *(const f16x4*)(gp + 512);
            nn2 = *(const f16x4*)(gp + 1024);
            na  = att[(size_t)sn * BDIM + g * 32 + i];
        }
        __syncthreads();

        // --- MFMA: gh over K=512, wave w -> ghsT cols w*16..+16 ---
        f32x4 acc0 = {0.f, 0.f, 0.f, 0.f};
        f32x4 acc1 = {0.f, 0.f, 0.f, 0.f};
        #pragma unroll
        for (int kk = 0; kk < 16; ++kk) {
            const int kb = kk * 64 + k8 * 2;
            const int b0 = (rr0 * 1024 + kb) ^ ((rr0 & 7) << 4);
            const int b1 = (rr1 * 1024 + kb) ^ ((rr1 & 7) << 4);
            const f16x8 a0 = *(const f16x8*)((const char*)h16 + b0);
            const f16x8 a1 = *(const f16x8*)((const char*)h16 + b1);
            acc0 = __builtin_amdgcn_mfma_f32_16x16x32_f16(a0, B[kk], acc0, 0, 0, 0);
            acc1 = __builtin_amdgcn_mfma_f32_16x16x32_f16(a1, B[kk], acc1, 0, 0, 0);
        }
        #pragma unroll
        for (int q = 0; q < 4; ++q) {
            ghsT[ib + q][nl]      = acc0[q];
            ghsT[16 + ib + q][nl] = acc1[q];
        }
        __syncthreads();

        // --- gates + h update; fire single data+seq store (no ack wait) ---
        const int wr = (rd == 2) ? 0 : rd + 1;
        if (t < 256) {
            const float4 ghr = *(const float4*)&ghsT[i][j4];
            const float4 ghz = *(const float4*)&ghsT[i][32 + j4];
            const float4 ghn = *(const float4*)&ghsT[i][64 + j4];
            const float hrr[4] = {ghr.x, ghr.y, ghr.z, ghr.w};
            const float hzz[4] = {ghz.x, ghz.y, ghz.z, ghz.w};
            const float hnn[4] = {ghn.x, ghn.y, ghn.z, ghn.w};
            float o[4];
            f16x4 hp;
            #pragma unroll
            for (int q = 0; q < 4; ++q) {
                const float hr = hrr[q] + bhr[q];
                const float hz = hzz[q] + bhz[q];
                const float hn = hnn[q] + bhn[q];
                const float h  = hv[q];
                const float rg = 1.f / (1.f + __expf(-((float)cr[q] + hr)));
                const float zg = 1.f / (1.f + __expf(-((float)cz[q] + hz)));
                const float ng = tanhf((float)cn[q] + rg * hn);
                const float ho = (1.f - zg) * ng + zg * h;
                const float hnew = (1.f - ca) * h + ca * ho;
                hv[q] = hnew;
                o[q] = hnew;
                hp[q] = (_Float16)hnew;
            }
            union { f16x4 v; unsigned int d[2]; } pk; pk.v = hp;
            u32x4 st;
            st[0] = pk.d[0]; st[1] = pk.d[1];
            st[2] = (unsigned)(s + 1); st[3] = (unsigned)(s + 1);
            char* hd = hb2c + ((size_t)wr * 65536
                     + (size_t)(g * 32 + i) * 128 + (size_t)c * 8 + (t & 7)) * 16;
            asm volatile("global_store_dwordx4 %0, %1, off sc0 sc1"
                         :: "v"(hd), "v"(st) : "memory");
            // out store after the exchange store: off the critical path
            *(float4*)(out + ((size_t)(g * 32 + i) * LDIM + s) * HDIM + c * 32 + j4)
                = *(float4*)o;
        }
        cr = nr; cz = nz; cn = nn2; ca = na;
        rd = wr;
    }

    if (t < 256) {
        float o[4] = {hv[0], hv[1], hv[2], hv[3]};
        *(float4*)(hx + (size_t)(g * 32 + i) * 512 + c * 32 + j4) = *(float4*)o;
    }
}

// ---------------------------------------------------------------------------
extern "C" void kernel_launch(void* const* d_in, const int* in_sizes, int n_in,
                              void* d_out, int out_size, void* d_ws, size_t ws_size,
                              hipStream_t stream)
{
    const float* x   = (const float*)d_in[0];
    const float* att = (const float*)d_in[1];
    const float* h0  = (const float*)d_in[2];
    const float* wih = (const float*)d_in[3];
    const float* whh = (const float*)d_in[4];
    const float* bih = (const float*)d_in[5];
    const float* bhh = (const float*)d_in[6];

    float* out = (float*)d_out;
    float* hx  = out + (size_t)BDIM * LDIM * HDIM;

    // ws layout:
    //   wfA @ 0x000000  (1.5MB fragment-packed weights; reused wfi->wfh)
    //   hb2 @ 0x180000  (3 x 1MB  {payload,seq} exchange units)
    //   gx  @ 0x480000  (~302MB f16)
    char* ws = (char*)d_ws;
    f16x8*    wfA = (f16x8*)ws;
    char*     hb2 = ws + 0x180000;
    _Float16* gx  = (_Float16*)(ws + 0x480000);

    k_init<<<256, 256, 0, stream>>>(h0, (u32x4*)hb2);
    k_pack_wfi<<<384, 256, 0, stream>>>(wih, wfA);
    k_gemm_gx<<<4800, 256, 0, stream>>>(x, wfA, bih, gx);
    k_pack_wfh<<<384, 256, 0, stream>>>(whh, wfA);   // overwrites wfi (gemm done)
    k_recur<<<256, 384, 0, stream>>>(gx, att, h0, wfA, bhh, hb2, out, hx);
}

// Round 16
// 1359.478 us; speedup vs baseline: 1.0642x; 1.0642x over previous
//
#include <hip/hip_runtime.h>
#include <hip/hip_fp16.h>

#define LDIM 200
#define BDIM 512
#define IDIM 512
#define HDIM 512
#define GDIM 1536  // 3*H

typedef _Float16 f16x8 __attribute__((ext_vector_type(8)));
typedef _Float16 f16x4 __attribute__((ext_vector_type(4)));
typedef float    f32x4 __attribute__((ext_vector_type(4)));
typedef unsigned int u32x4 __attribute__((ext_vector_type(4)));

// ---------------------------------------------------------------------------
// k_init: seed hb2 buf0 with {h0 payload, seq=0}; invalidate bufs 1,2 with
// seq=0xFFFFFFFF (cross-replay stale-seq kill — round-12 verified).
// ---------------------------------------------------------------------------
__global__ __launch_bounds__(256) void k_init(
    const float* __restrict__ h0, u32x4* __restrict__ hb2)
{
    int u = blockIdx.x * 256 + threadIdx.x;
    if (u >= BDIM * HDIM / 4) return;
    const int row = u >> 7, col4 = u & 127;
    const float4 v = *(const float4*)(h0 + (size_t)row * HDIM + col4 * 4);
    union { f16x4 h; unsigned int d[2]; } pk;
    pk.h[0] = (_Float16)v.x; pk.h[1] = (_Float16)v.y;
    pk.h[2] = (_Float16)v.z; pk.h[3] = (_Float16)v.w;
    u32x4 st; st[0] = pk.d[0]; st[1] = pk.d[1]; st[2] = 0u; st[3] = 0u;
    hb2[u] = st;
    u32x4 inv; inv[0] = 0u; inv[1] = 0u;
    inv[2] = 0xFFFFFFFFu; inv[3] = 0xFFFFFFFFu;
    hb2[u + 65536]  = inv;   // buf1
    hb2[u + 131072] = inv;   // buf2
}

// ---------------------------------------------------------------------------
// k_pack_wfi: pack w_ih (f32 [1536][512]) into MFMA B-fragment order, f16.
// (round-3 verified)
// ---------------------------------------------------------------------------
__global__ __launch_bounds__(256) void k_pack_wfi(
    const float* __restrict__ w, f16x8* __restrict__ wf)
{
    int u = blockIdx.x * 256 + threadIdx.x;
    if (u >= (GDIM / 16) * 16 * 64) return;
    const int lane = u & 63;
    const int kk   = (u >> 6) & 15;
    const int ntg  = u >> 10;
    const int n = ntg * 16 + (lane & 15);
    const int k = kk * 32 + (lane >> 4) * 8;
    const float* src = w + (size_t)n * IDIM + k;
    f16x8 v;
    #pragma unroll
    for (int j = 0; j < 8; ++j) v[j] = (_Float16)src[j];
    wf[u] = v;
}

// ---------------------------------------------------------------------------
// k_pack_wfh: pack w_hh into per-colgroup fragment order. (round-3 verified)
// ---------------------------------------------------------------------------
__global__ __launch_bounds__(256) void k_pack_wfh(
    const float* __restrict__ w, f16x8* __restrict__ wf)
{
    int u = blockIdx.x * 256 + threadIdx.x;
    if (u >= 16 * 6 * 16 * 64) return;
    const int lane = u & 63;
    const int kk   = (u >> 6) & 15;
    const int cw   = u >> 10;
    const int wv   = cw % 6;
    const int c    = cw / 6;
    const int n_local = wv * 16 + (lane & 15);
    const int gate    = n_local >> 5;
    const int j_local = n_local & 31;
    const int n = gate * 512 + c * 32 + j_local;
    const int k = kk * 32 + (lane >> 4) * 8;
    const float* src = w + (size_t)n * HDIM + k;
    f16x8 v;
    #pragma unroll
    for (int j = 0; j < 8; ++j) v[j] = (_Float16)src[j];
    wf[u] = v;
}

// ---------------------------------------------------------------------------
// K1 v2: gx = x @ w_ih^T + b_ih (f16 out). (round-6/7 verified staging —
// the r12 "coalesced" variant was a measured regression and stays reverted.)
// ---------------------------------------------------------------------------
__global__ __launch_bounds__(256, 2) void k_gemm_gx(
    const float* __restrict__ x, const f16x8* __restrict__ wfi,
    const float* __restrict__ bih, _Float16* __restrict__ gx)
{
    const int bid  = blockIdx.x;
    const int xcd  = bid & 7;
    const int slot = bid >> 3;          // 0..599
    const int gl   = slot / 3;          // 0..199
    const int ng   = slot % 3;          // 0..2
    const int m0   = (xcd * 200 + gl) * 64;
    const int n0   = ng * 512;

    const int t   = threadIdx.x;
    const int wid = t >> 6;             // n-quarter 0..3
    const int l   = t & 63;

    __shared__ __align__(16) _Float16 As[64 * 512];    // 64KB, XOR-swizzled

    {
        const int r  = t >> 2;
        const int k0 = (t & 3) * 128;
        const int m  = m0 + r;
        const float* src = x + ((size_t)(m & 511) * LDIM + (m >> 9)) * IDIM + k0;
        #pragma unroll
        for (int jj = 0; jj < 16; ++jj) {
            const float4 v0 = *(const float4*)(src + jj * 8);
            const float4 v1 = *(const float4*)(src + jj * 8 + 4);
            f16x8 hq;
            hq[0] = (_Float16)v0.x; hq[1] = (_Float16)v0.y;
            hq[2] = (_Float16)v0.z; hq[3] = (_Float16)v0.w;
            hq[4] = (_Float16)v1.x; hq[5] = (_Float16)v1.y;
            hq[6] = (_Float16)v1.z; hq[7] = (_Float16)v1.w;
            const int byte = (r * 1024 + (k0 + jj * 8) * 2) ^ ((r & 7) << 4);
            *(f16x8*)((char*)As + byte) = hq;
        }
    }
    __syncthreads();

    const f16x8* bp = wfi + (size_t)((ng * 4 + wid) * 8) * 1024 + l;
    const int kb8   = (l >> 4) * 16;
    const int rbase = l & 15;

    f32x4 acc[4][8] = {};

    for (int kk = 0; kk < 16; ++kk) {
        f16x8 a[4];
        #pragma unroll
        for (int mt = 0; mt < 4; ++mt) {
            const int r = mt * 16 + rbase;
            const int byte = (r * 1024 + kk * 64 + kb8) ^ ((r & 7) << 4);
            a[mt] = *(const f16x8*)((const char*)As + byte);
        }
        const f16x8* bk = bp + kk * 64;
        #pragma unroll
        for (int nt = 0; nt < 8; ++nt) {
            const f16x8 bf = bk[(size_t)nt * 1024];
            #pragma unroll
            for (int mt = 0; mt < 4; ++mt)
                acc[mt][nt] = __builtin_amdgcn_mfma_f32_16x16x32_f16(a[mt], bf, acc[mt][nt], 0, 0, 0);
        }
    }

    #pragma unroll
    for (int nt = 0; nt < 8; ++nt) {
        const int n = n0 + wid * 128 + nt * 16 + (l & 15);
        const float bv = bih[n];
        #pragma unroll
        for (int mt = 0; mt < 4; ++mt) {
            #pragma unroll
            for (int r = 0; r < 4; ++r) {
                const int m = m0 + mt * 16 + (l >> 4) * 4 + r;
                gx[(size_t)m * GDIM + n] = (_Float16)(acc[mt][nt][r] + bv);
            }
        }
    }
}

// ---------------------------------------------------------------------------
// K2: persistent recurrence.  (round-7/12 verified, byte-identical)
// 256 blocks = 16 batch-groups x 16 col-groups, 384 threads. w_hh slice in
// registers. Exchange: each 16B unit = {f16x4 h payload, seq, seq}; producer
// fires ONE dwordx4 sc0sc1 store; consumers poll their own units until
// seq == s. One IF round-trip per step. 3-buffer rotation (skew<=1 proof).
// ---------------------------------------------------------------------------
__global__ __launch_bounds__(384) void k_recur(
    const _Float16* __restrict__ gx, const float* __restrict__ att,
    const float* __restrict__ h0, const f16x8* __restrict__ wfh,
    const float* __restrict__ bhh, char* __restrict__ hb2c,
    float* __restrict__ out, float* __restrict__ hx)
{
    const int bid = blockIdx.x;
    const int g = bid >> 4;
    const int c = bid & 15;
    const int t = threadIdx.x;
    const int w = t >> 6;                        // 0..5
    const int l = t & 63;

    __shared__ __align__(16) _Float16 h16[32 * 512];   // 32KB, XOR-swizzled
    __shared__ float ghsT[32][100];                    // gh slice [row][n]

    // --- B fragments: wave w holds its 16 kk-frags in registers forever ---
    f16x8 B[16];
    {
        const f16x8* p = wfh + (size_t)(c * 6 + w) * 1024 + l;
        #pragma unroll
        for (int kk = 0; kk < 16; ++kk) B[kk] = p[kk * 64];
    }

    // --- gate-phase mapping: thread t<256 owns row i, cols j4..j4+3 ---
    const int i  = t >> 3;
    const int j4 = (t & 7) * 4;

    float bhr[4], bhz[4], bhn[4], hv[4];
    if (t < 256) {
        const float4 r4 = *(const float4*)(bhh + c * 32 + j4);
        const float4 z4 = *(const float4*)(bhh + 512 + c * 32 + j4);
        const float4 n4 = *(const float4*)(bhh + 1024 + c * 32 + j4);
        bhr[0]=r4.x; bhr[1]=r4.y; bhr[2]=r4.z; bhr[3]=r4.w;
        bhz[0]=z4.x; bhz[1]=z4.y; bhz[2]=z4.z; bhz[3]=z4.w;
        bhn[0]=n4.x; bhn[1]=n4.y; bhn[2]=n4.z; bhn[3]=n4.w;
        const float4 h4 = *(const float4*)(h0 + (size_t)(g * 32 + i) * 512 + c * 32 + j4);
        hv[0]=h4.x; hv[1]=h4.y; hv[2]=h4.z; hv[3]=h4.w;
    }

    const int ib = (l >> 4) * 4;
    const int nl = w * 16 + (l & 15);
    const int k8 = (l >> 4) * 8;
    const int rr0 = l & 15;
    const int rr1 = rr0 + 16;

    // --- prologue: gate inputs for step 0 ---
    f16x4 cr = {}, cz = {}, cn = {};
    float ca = 0.f;
    if (t < 256) {
        const _Float16* gp = gx + ((size_t)(g * 32 + i)) * GDIM + c * 32 + j4;
        cr = *(const f16x4*)(gp);
        cz = *(const f16x4*)(gp + 512);
        cn = *(const f16x4*)(gp + 1024);
        ca = att[g * 32 + i];
    }

    int rd = 0;                                  // hb2 read buffer = s % 3
    for (int s = 0; s < LDIM; ++s) {
        // --- fused poll+load: wait until all 16 of my units carry seq==s ---
        u32x4 vv[16];
        if (t < 256) {
            const char* hbase = hb2c
                + ((size_t)rd * 65536 + (size_t)g * 4096 + t) * 16;
            bool again = true;
            while (again) {
                #pragma unroll
                for (int q = 0; q < 16; ++q)
                    asm volatile("global_load_dwordx4 %0, %1, off sc0 sc1"
                                 : "=v"(vv[q]) : "v"(hbase + (size_t)q * 4096));
                asm volatile("s_waitcnt vmcnt(0)" ::: "memory");
                again = false;
                #pragma unroll
                for (int q = 0; q < 16; ++q)
                    again |= (vv[q][2] != (unsigned)s);
            }
            __builtin_amdgcn_sched_barrier(0);
            #pragma unroll
            for (int q = 0; q < 16; ++q) {
                const int idx = q * 256 + t;     // u64 payload, row-major
                const int row = idx >> 7;        // 128 units per row
                const int c8  = idx & 127;
                const int byte = (row * 1024 + c8 * 8) ^ ((row & 7) << 4);
                union { unsigned int d[2]; unsigned long long u; } m;
                m.d[0] = vv[q][0]; m.d[1] = vv[q][1];
                *(unsigned long long*)((char*)h16 + byte) = m.u;
            }
        }

        // --- 1-step-ahead gate prefetch (hidden under MFMA + gates) ---
        f16x4 nr = {}, nz = {}, nn2 = {};
        float na = 0.f;
        if (t < 256) {
            const int sn = (s < LDIM - 1) ? s + 1 : s;
            const _Float16* gp = gx + ((size_t)sn * BDIM + g * 32 + i) * GDIM + c * 32 + j4;
            nr  = *(const f16x4*)(gp);
            nz  = *(const f16x4*)(gp + 512);
            nn2 = *(const f16x4*)(gp + 1024);
            na  = att[(size_t)sn * BDIM + g * 32 + i];
        }
        __syncthreads();

        // --- MFMA: gh over K=512, wave w -> ghsT cols w*16..+16 ---
        f32x4 acc0 = {0.f, 0.f, 0.f, 0.f};
        f32x4 acc1 = {0.f, 0.f, 0.f, 0.f};
        #pragma unroll
        for (int kk = 0; kk < 16; ++kk) {
            const int kb = kk * 64 + k8 * 2;
            const int b0 = (rr0 * 1024 + kb) ^ ((rr0 & 7) << 4);
            const int b1 = (rr1 * 1024 + kb) ^ ((rr1 & 7) << 4);
            const f16x8 a0 = *(const f16x8*)((const char*)h16 + b0);
            const f16x8 a1 = *(const f16x8*)((const char*)h16 + b1);
            acc0 = __builtin_amdgcn_mfma_f32_16x16x32_f16(a0, B[kk], acc0, 0, 0, 0);
            acc1 = __builtin_amdgcn_mfma_f32_16x16x32_f16(a1, B[kk], acc1, 0, 0, 0);
        }
        #pragma unroll
        for (int q = 0; q < 4; ++q) {
            ghsT[ib + q][nl]      = acc0[q];
            ghsT[16 + ib + q][nl] = acc1[q];
        }
        __syncthreads();

        // --- gates + h update; fire single data+seq store (no ack wait) ---
        const int wr = (rd == 2) ? 0 : rd + 1;
        if (t < 256) {
            const float4 ghr = *(const float4*)&ghsT[i][j4];
            const float4 ghz = *(const float4*)&ghsT[i][32 + j4];
            const float4 ghn = *(const float4*)&ghsT[i][64 + j4];
            const float hrr[4] = {ghr.x, ghr.y, ghr.z, ghr.w};
            const float hzz[4] = {ghz.x, ghz.y, ghz.z, ghz.w};
            const float hnn[4] = {ghn.x, ghn.y, ghn.z, ghn.w};
            float o[4];
            f16x4 hp;
            #pragma unroll
            for (int q = 0; q < 4; ++q) {
                const float hr = hrr[q] + bhr[q];
                const float hz = hzz[q] + bhz[q];
                const float hn = hnn[q] + bhn[q];
                const float h  = hv[q];
                const float rg = 1.f / (1.f + __expf(-((float)cr[q] + hr)));
                const float zg = 1.f / (1.f + __expf(-((float)cz[q] + hz)));
                const float ng = tanhf((float)cn[q] + rg * hn);
                const float ho = (1.f - zg) * ng + zg * h;
                const float hnew = (1.f - ca) * h + ca * ho;
                hv[q] = hnew;
                o[q] = hnew;
                hp[q] = (_Float16)hnew;
            }
            union { f16x4 v; unsigned int d[2]; } pk; pk.v = hp;
            u32x4 st;
            st[0] = pk.d[0]; st[1] = pk.d[1];
            st[2] = (unsigned)(s + 1); st[3] = (unsigned)(s + 1);
            char* hd = hb2c + ((size_t)wr * 65536
                     + (size_t)(g * 32 + i) * 128 + (size_t)c * 8 + (t & 7)) * 16;
            asm volatile("global_store_dwordx4 %0, %1, off sc0 sc1"
                         :: "v"(hd), "v"(st) : "memory");
            // out store after the exchange store: off the critical path
            *(float4*)(out + ((size_t)(g * 32 + i) * LDIM + s) * HDIM + c * 32 + j4)
                = *(float4*)o;
        }
        cr = nr; cz = nz; cn = nn2; ca = na;
        rd = wr;
        // no loop-end barrier needed: next-step LDS writes are fenced by the
        // post-stage __syncthreads; gates (waves 0-3) precede staging in
        // program order; waves 4-5 wait at the post-stage barrier.
    }

    if (t < 256) {
        float o[4] = {hv[0], hv[1], hv[2], hv[3]};
        *(float4*)(hx + (size_t)(g * 32 + i) * 512 + c * 32 + j4) = *(float4*)o;
    }
}

// ---------------------------------------------------------------------------
extern "C" void kernel_launch(void* const* d_in, const int* in_sizes, int n_in,
                              void* d_out, int out_size, void* d_ws, size_t ws_size,
                              hipStream_t stream)
{
    const float* x   = (const float*)d_in[0];
    const float* att = (const float*)d_in[1];
    const float* h0  = (const float*)d_in[2];
    const float* wih = (const float*)d_in[3];
    const float* whh = (const float*)d_in[4];
    const float* bih = (const float*)d_in[5];
    const float* bhh = (const float*)d_in[6];

    float* out = (float*)d_out;
    float* hx  = out + (size_t)BDIM * LDIM * HDIM;

    // ws layout:
    //   wfA @ 0x000000  (1.5MB fragment-packed weights; reused wfi->wfh)
    //   hb2 @ 0x180000  (3 x 1MB  {payload,seq} exchange units)
    //   gx  @ 0x480000  (~302MB f16)
    char* ws = (char*)d_ws;
    f16x8*    wfA = (f16x8*)ws;
    char*     hb2 = ws + 0x180000;
    _Float16* gx  = (_Float16*)(ws + 0x480000);

    k_init<<<256, 256, 0, stream>>>(h0, (u32x4*)hb2);
    k_pack_wfi<<<384, 256, 0, stream>>>(wih, wfA);
    k_gemm_gx<<<4800, 256, 0, stream>>>(x, wfA, bih, gx);
    k_pack_wfh<<<384, 256, 0, stream>>>(whh, wfA);   // overwrites wfi (gemm done)
    k_recur<<<256, 384, 0, stream>>>(gx, att, h0, wfA, bhh, hb2, out, hx);
}

// Round 17
// 1245.147 us; speedup vs baseline: 1.1619x; 1.0918x over previous
//
#include <hip/hip_runtime.h>
#include <hip/hip_fp16.h>

#define LDIM 200
#define BDIM 512
#define IDIM 512
#define HDIM 512
#define GDIM 1536  // 3*H

typedef _Float16 f16x8 __attribute__((ext_vector_type(8)));
typedef _Float16 f16x4 __attribute__((ext_vector_type(4)));
typedef float    f32x4 __attribute__((ext_vector_type(4)));
typedef unsigned int u32x4 __attribute__((ext_vector_type(4)));

// ---------------------------------------------------------------------------
// k_init: seed hb2 buf0 with {h0 payload, seq=0}; invalidate bufs 1,2 with
// seq=0xFFFFFFFF (cross-replay stale-seq kill — round-12 verified).
// ---------------------------------------------------------------------------
__global__ __launch_bounds__(256) void k_init(
    const float* __restrict__ h0, u32x4* __restrict__ hb2)
{
    int u = blockIdx.x * 256 + threadIdx.x;
    if (u >= BDIM * HDIM / 4) return;
    const int row = u >> 7, col4 = u & 127;
    const float4 v = *(const float4*)(h0 + (size_t)row * HDIM + col4 * 4);
    union { f16x4 h; unsigned int d[2]; } pk;
    pk.h[0] = (_Float16)v.x; pk.h[1] = (_Float16)v.y;
    pk.h[2] = (_Float16)v.z; pk.h[3] = (_Float16)v.w;
    u32x4 st; st[0] = pk.d[0]; st[1] = pk.d[1]; st[2] = 0u; st[3] = 0u;
    hb2[u] = st;
    u32x4 inv; inv[0] = 0u; inv[1] = 0u;
    inv[2] = 0xFFFFFFFFu; inv[3] = 0xFFFFFFFFu;
    hb2[u + 65536]  = inv;   // buf1
    hb2[u + 131072] = inv;   // buf2
}

// ---------------------------------------------------------------------------
// k_pack_wfi: pack w_ih (f32 [1536][512]) into MFMA B-fragment order, f16.
// (round-3 verified)
// ---------------------------------------------------------------------------
__global__ __launch_bounds__(256) void k_pack_wfi(
    const float* __restrict__ w, f16x8* __restrict__ wf)
{
    int u = blockIdx.x * 256 + threadIdx.x;
    if (u >= (GDIM / 16) * 16 * 64) return;
    const int lane = u & 63;
    const int kk   = (u >> 6) & 15;
    const int ntg  = u >> 10;
    const int n = ntg * 16 + (lane & 15);
    const int k = kk * 32 + (lane >> 4) * 8;
    const float* src = w + (size_t)n * IDIM + k;
    f16x8 v;
    #pragma unroll
    for (int j = 0; j < 8; ++j) v[j] = (_Float16)src[j];
    wf[u] = v;
}

// ---------------------------------------------------------------------------
// k_pack_wfh: pack w_hh into per-colgroup fragment order. (round-3 verified)
// ---------------------------------------------------------------------------
__global__ __launch_bounds__(256) void k_pack_wfh(
    const float* __restrict__ w, f16x8* __restrict__ wf)
{
    int u = blockIdx.x * 256 + threadIdx.x;
    if (u >= 16 * 6 * 16 * 64) return;
    const int lane = u & 63;
    const int kk   = (u >> 6) & 15;
    const int cw   = u >> 10;
    const int wv   = cw % 6;
    const int c    = cw / 6;
    const int n_local = wv * 16 + (lane & 15);
    const int gate    = n_local >> 5;
    const int j_local = n_local & 31;
    const int n = gate * 512 + c * 32 + j_local;
    const int k = kk * 32 + (lane >> 4) * 8;
    const float* src = w + (size_t)n * HDIM + k;
    f16x8 v;
    #pragma unroll
    for (int j = 0; j < 8; ++j) v[j] = (_Float16)src[j];
    wf[u] = v;
}

// ---------------------------------------------------------------------------
// K1 v4: gx = x @ w_ih^T + b_ih (f16 out).  Round-6/7-verified structure;
// ONLY change: B-fragment stream is software-pipelined one kk ahead in
// registers (plain C loads; compiler-managed waits). Removes the serial
// ~200cy L2-hit latency per kk that made the loop latency-bound. Per-acc
// MFMA order unchanged -> bitwise-identical gx.
// ---------------------------------------------------------------------------
__global__ __launch_bounds__(256, 2) void k_gemm_gx(
    const float* __restrict__ x, const f16x8* __restrict__ wfi,
    const float* __restrict__ bih, _Float16* __restrict__ gx)
{
    const int bid  = blockIdx.x;
    const int xcd  = bid & 7;
    const int slot = bid >> 3;          // 0..599
    const int gl   = slot / 3;          // 0..199
    const int ng   = slot % 3;          // 0..2
    const int m0   = (xcd * 200 + gl) * 64;
    const int n0   = ng * 512;

    const int t   = threadIdx.x;
    const int wid = t >> 6;             // n-quarter 0..3
    const int l   = t & 63;

    __shared__ __align__(16) _Float16 As[64 * 512];    // 64KB, XOR-swizzled

    {
        const int r  = t >> 2;
        const int k0 = (t & 3) * 128;
        const int m  = m0 + r;
        const float* src = x + ((size_t)(m & 511) * LDIM + (m >> 9)) * IDIM + k0;
        #pragma unroll
        for (int jj = 0; jj < 16; ++jj) {
            const float4 v0 = *(const float4*)(src + jj * 8);
            const float4 v1 = *(const float4*)(src + jj * 8 + 4);
            f16x8 hq;
            hq[0] = (_Float16)v0.x; hq[1] = (_Float16)v0.y;
            hq[2] = (_Float16)v0.z; hq[3] = (_Float16)v0.w;
            hq[4] = (_Float16)v1.x; hq[5] = (_Float16)v1.y;
            hq[6] = (_Float16)v1.z; hq[7] = (_Float16)v1.w;
            const int byte = (r * 1024 + (k0 + jj * 8) * 2) ^ ((r & 7) << 4);
            *(f16x8*)((char*)As + byte) = hq;
        }
    }
    __syncthreads();

    const f16x8* bp = wfi + (size_t)((ng * 4 + wid) * 8) * 1024 + l;
    const int kb8   = (l >> 4) * 16;
    const int rbase = l & 15;

    f32x4 acc[4][8] = {};

    // --- B double-buffer: prefetch kk+1 while computing kk ---
    f16x8 bcur[8];
    #pragma unroll
    for (int nt = 0; nt < 8; ++nt) bcur[nt] = bp[(size_t)nt * 1024];   // kk=0

    for (int kk = 0; kk < 16; ++kk) {
        f16x8 bnx[8];
        {
            const f16x8* bk = bp + ((kk + 1) & 15) * 64;   // wrap: last discarded
            #pragma unroll
            for (int nt = 0; nt < 8; ++nt) bnx[nt] = bk[(size_t)nt * 1024];
        }
        f16x8 a[4];
        #pragma unroll
        for (int mt = 0; mt < 4; ++mt) {
            const int r = mt * 16 + rbase;
            const int byte = (r * 1024 + kk * 64 + kb8) ^ ((r & 7) << 4);
            a[mt] = *(const f16x8*)((const char*)As + byte);
        }
        #pragma unroll
        for (int nt = 0; nt < 8; ++nt) {
            #pragma unroll
            for (int mt = 0; mt < 4; ++mt)
                acc[mt][nt] = __builtin_amdgcn_mfma_f32_16x16x32_f16(a[mt], bcur[nt], acc[mt][nt], 0, 0, 0);
        }
        #pragma unroll
        for (int nt = 0; nt < 8; ++nt) bcur[nt] = bnx[nt];
    }

    #pragma unroll
    for (int nt = 0; nt < 8; ++nt) {
        const int n = n0 + wid * 128 + nt * 16 + (l & 15);
        const float bv = bih[n];
        #pragma unroll
        for (int mt = 0; mt < 4; ++mt) {
            #pragma unroll
            for (int r = 0; r < 4; ++r) {
                const int m = m0 + mt * 16 + (l >> 4) * 4 + r;
                gx[(size_t)m * GDIM + n] = (_Float16)(acc[mt][nt][r] + bv);
            }
        }
    }
}

// ---------------------------------------------------------------------------
// K2: persistent recurrence.  (round-7/12/16 verified, byte-identical)
// 256 blocks = 16 batch-groups x 16 col-groups, 384 threads. w_hh slice in
// registers. Exchange: each 16B unit = {f16x4 h payload, seq, seq}; producer
// fires ONE dwordx4 sc0sc1 store; consumers poll their own units until
// seq == s. One IF round-trip per step. 3-buffer rotation (skew<=1 proof).
// ---------------------------------------------------------------------------
__global__ __launch_bounds__(384) void k_recur(
    const _Float16* __restrict__ gx, const float* __restrict__ att,
    const float* __restrict__ h0, const f16x8* __restrict__ wfh,
    const float* __restrict__ bhh, char* __restrict__ hb2c,
    float* __restrict__ out, float* __restrict__ hx)
{
    const int bid = blockIdx.x;
    const int g = bid >> 4;
    const int c = bid & 15;
    const int t = threadIdx.x;
    const int w = t >> 6;                        // 0..5
    const int l = t & 63;

    __shared__ __align__(16) _Float16 h16[32 * 512];   // 32KB, XOR-swizzled
    __shared__ float ghsT[32][100];                    // gh slice [row][n]

    // --- B fragments: wave w holds its 16 kk-frags in registers forever ---
    f16x8 B[16];
    {
        const f16x8* p = wfh + (size_t)(c * 6 + w) * 1024 + l;
        #pragma unroll
        for (int kk = 0; kk < 16; ++kk) B[kk] = p[kk * 64];
    }

    // --- gate-phase mapping: thread t<256 owns row i, cols j4..j4+3 ---
    const int i  = t >> 3;
    const int j4 = (t & 7) * 4;

    float bhr[4], bhz[4], bhn[4], hv[4];
    if (t < 256) {
        const float4 r4 = *(const float4*)(bhh + c * 32 + j4);
        const float4 z4 = *(const float4*)(bhh + 512 + c * 32 + j4);
        const float4 n4 = *(const float4*)(bhh + 1024 + c * 32 + j4);
        bhr[0]=r4.x; bhr[1]=r4.y; bhr[2]=r4.z; bhr[3]=r4.w;
        bhz[0]=z4.x; bhz[1]=z4.y; bhz[2]=z4.z; bhz[3]=z4.w;
        bhn[0]=n4.x; bhn[1]=n4.y; bhn[2]=n4.z; bhn[3]=n4.w;
        const float4 h4 = *(const float4*)(h0 + (size_t)(g * 32 + i) * 512 + c * 32 + j4);
        hv[0]=h4.x; hv[1]=h4.y; hv[2]=h4.z; hv[3]=h4.w;
    }

    const int ib = (l >> 4) * 4;
    const int nl = w * 16 + (l & 15);
    const int k8 = (l >> 4) * 8;
    const int rr0 = l & 15;
    const int rr1 = rr0 + 16;

    // --- prologue: gate inputs for step 0 ---
    f16x4 cr = {}, cz = {}, cn = {};
    float ca = 0.f;
    if (t < 256) {
        const _Float16* gp = gx + ((size_t)(g * 32 + i)) * GDIM + c * 32 + j4;
        cr = *(const f16x4*)(gp);
        cz = *(const f16x4*)(gp + 512);
        cn = *(const f16x4*)(gp + 1024);
        ca = att[g * 32 + i];
    }

    int rd = 0;                                  // hb2 read buffer = s % 3
    for (int s = 0; s < LDIM; ++s) {
        // --- fused poll+load: wait until all 16 of my units carry seq==s ---
        u32x4 vv[16];
        if (t < 256) {
            const char* hbase = hb2c
                + ((size_t)rd * 65536 + (size_t)g * 4096 + t) * 16;
            bool again = true;
            while (again) {
                #pragma unroll
                for (int q = 0; q < 16; ++q)
                    asm volatile("global_load_dwordx4 %0, %1, off sc0 sc1"
                                 : "=v"(vv[q]) : "v"(hbase + (size_t)q * 4096));
                asm volatile("s_waitcnt vmcnt(0)" ::: "memory");
                again = false;
                #pragma unroll
                for (int q = 0; q < 16; ++q)
                    again |= (vv[q][2] != (unsigned)s);
            }
            __builtin_amdgcn_sched_barrier(0);
            #pragma unroll
            for (int q = 0; q < 16; ++q) {
                const int idx = q * 256 + t;     // u64 payload, row-major
                const int row = idx >> 7;        // 128 units per row
                const int c8  = idx & 127;
                const int byte = (row * 1024 + c8 * 8) ^ ((row & 7) << 4);
                union { unsigned int d[2]; unsigned long long u; } m;
                m.d[0] = vv[q][0]; m.d[1] = vv[q][1];
                *(unsigned long long*)((char*)h16 + byte) = m.u;
            }
        }

        // --- 1-step-ahead gate prefetch (hidden under MFMA + gates) ---
        f16x4 nr = {}, nz = {}, nn2 = {};
        float na = 0.f;
        if (t < 256) {
            const int sn = (s < LDIM - 1) ? s + 1 : s;
            const _Float16* gp = gx + ((size_t)sn * BDIM + g * 32 + i) * GDIM + c * 32 + j4;
            nr  = *(const f16x4*)(gp);
            nz  = *(const f16x4*)(gp + 512);
            nn2 = *(const f16x4*)(gp + 1024);
            na  = att[(size_t)sn * BDIM + g * 32 + i];
        }
        __syncthreads();

        // --- MFMA: gh over K=512, wave w -> ghsT cols w*16..+16 ---
        f32x4 acc0 = {0.f, 0.f, 0.f, 0.f};
        f32x4 acc1 = {0.f, 0.f, 0.f, 0.f};
        #pragma unroll
        for (int kk = 0; kk < 16; ++kk) {
            const int kb = kk * 64 + k8 * 2;
            const int b0 = (rr0 * 1024 + kb) ^ ((rr0 & 7) << 4);
            const int b1 = (rr1 * 1024 + kb) ^ ((rr1 & 7) << 4);
            const f16x8 a0 = *(const f16x8*)((const char*)h16 + b0);
            const f16x8 a1 = *(const f16x8*)((const char*)h16 + b1);
            acc0 = __builtin_amdgcn_mfma_f32_16x16x32_f16(a0, B[kk], acc0, 0, 0, 0);
            acc1 = __builtin_amdgcn_mfma_f32_16x16x32_f16(a1, B[kk], acc1, 0, 0, 0);
        }
        #pragma unroll
        for (int q = 0; q < 4; ++q) {
            ghsT[ib + q][nl]      = acc0[q];
            ghsT[16 + ib + q][nl] = acc1[q];
        }
        __syncthreads();

        // --- gates + h update; fire single data+seq store (no ack wait) ---
        const int wr = (rd == 2) ? 0 : rd + 1;
        if (t < 256) {
            const float4 ghr = *(const float4*)&ghsT[i][j4];
            const float4 ghz = *(const float4*)&ghsT[i][32 + j4];
            const float4 ghn = *(const float4*)&ghsT[i][64 + j4];
            const float hrr[4] = {ghr.x, ghr.y, ghr.z, ghr.w};
            const float hzz[4] = {ghz.x, ghz.y, ghz.z, ghz.w};
            const float hnn[4] = {ghn.x, ghn.y, ghn.z, ghn.w};
            float o[4];
            f16x4 hp;
            #pragma unroll
            for (int q = 0; q < 4; ++q) {
                const float hr = hrr[q] + bhr[q];
                const float hz = hzz[q] + bhz[q];
                const float hn = hnn[q] + bhn[q];
                const float h  = hv[q];
                const float rg = 1.f / (1.f + __expf(-((float)cr[q] + hr)));
                const float zg = 1.f / (1.f + __expf(-((float)cz[q] + hz)));
                const float ng = tanhf((float)cn[q] + rg * hn);
                const float ho = (1.f - zg) * ng + zg * h;
                const float hnew = (1.f - ca) * h + ca * ho;
                hv[q] = hnew;
                o[q] = hnew;
                hp[q] = (_Float16)hnew;
            }
            union { f16x4 v; unsigned int d[2]; } pk; pk.v = hp;
            u32x4 st;
            st[0] = pk.d[0]; st[1] = pk.d[1];
            st[2] = (unsigned)(s + 1); st[3] = (unsigned)(s + 1);
            char* hd = hb2c + ((size_t)wr * 65536
                     + (size_t)(g * 32 + i) * 128 + (size_t)c * 8 + (t & 7)) * 16;
            asm volatile("global_store_dwordx4 %0, %1, off sc0 sc1"
                         :: "v"(hd), "v"(st) : "memory");
            // out store after the exchange store: off the critical path
            *(float4*)(out + ((size_t)(g * 32 + i) * LDIM + s) * HDIM + c * 32 + j4)
                = *(float4*)o;
        }
        cr = nr; cz = nz; cn = nn2; ca = na;
        rd = wr;
        // no loop-end barrier needed: next-step LDS writes are fenced by the
        // post-stage __syncthreads; gates (waves 0-3) precede staging in
        // program order; waves 4-5 wait at the post-stage barrier.
    }

    if (t < 256) {
        float o[4] = {hv[0], hv[1], hv[2], hv[3]};
        *(float4*)(hx + (size_t)(g * 32 + i) * 512 + c * 32 + j4) = *(float4*)o;
    }
}

// ---------------------------------------------------------------------------
extern "C" void kernel_launch(void* const* d_in, const int* in_sizes, int n_in,
                              void* d_out, int out_size, void* d_ws, size_t ws_size,
                              hipStream_t stream)
{
    const float* x   = (const float*)d_in[0];
    const float* att = (const float*)d_in[1];
    const float* h0  = (const float*)d_in[2];
    const float* wih = (const float*)d_in[3];
    const float* whh = (const float*)d_in[4];
    const float* bih = (const float*)d_in[5];
    const float* bhh = (const float*)d_in[6];

    float* out = (float*)d_out;
    float* hx  = out + (size_t)BDIM * LDIM * HDIM;

    // ws layout:
    //   wfA @ 0x000000  (1.5MB fragment-packed weights; reused wfi->wfh)
    //   hb2 @ 0x180000  (3 x 1MB  {payload,seq} exchange units)
    //   gx  @ 0x480000  (~302MB f16)
    char* ws = (char*)d_ws;
    f16x8*    wfA = (f16x8*)ws;
    char*     hb2 = ws + 0x180000;
    _Float16* gx  = (_Float16*)(ws + 0x480000);

    k_init<<<256, 256, 0, stream>>>(h0, (u32x4*)hb2);
    k_pack_wfi<<<384, 256, 0, stream>>>(wih, wfA);
    k_gemm_gx<<<4800, 256, 0, stream>>>(x, wfA, bih, gx);
    k_pack_wfh<<<384, 256, 0, stream>>>(whh, wfA);   // overwrites wfi (gemm done)
    k_recur<<<256, 384, 0, stream>>>(gx, att, h0, wfA, bhh, hb2, out, hx);
}